// Round 5
// baseline (603.342 us; speedup 1.0000x reference)
//
#include <hip/hip_runtime.h>
#include <hip/hip_bf16.h>
#include <stdint.h>

#define HD 256
#define BM 64
#define APAD 8
#define ASTRIDE (HD + APAD)   // 264 ushorts

typedef __bf16 bf16x8 __attribute__((ext_vector_type(8)));
typedef float f32x4 __attribute__((ext_vector_type(4)));
typedef unsigned short ushort8v __attribute__((ext_vector_type(8)));
typedef unsigned short us4 __attribute__((ext_vector_type(4)));

__device__ __forceinline__ unsigned short f2bf(float f) {
    unsigned int x = __float_as_uint(f);
    unsigned int r = (x + 0x7FFFu + ((x >> 16) & 1u)) >> 16;
    return (unsigned short)r;
}
__device__ __forceinline__ float bf2f(unsigned short h) {
    return __uint_as_float(((unsigned)h) << 16);
}

// ---------------- K1: scan (block 0) + weight transpose/convert (blocks 1..256) ----------------
__global__ void setup_kernel(const int* __restrict__ seq_len, int* __restrict__ offsets, int B,
                             const float* __restrict__ Wp, const float* __restrict__ W1,
                             const float* __restrict__ W2,
                             unsigned short* __restrict__ WphT, unsigned short* __restrict__ WpbT,
                             unsigned short* __restrict__ W1b, unsigned short* __restrict__ W2T) {
    int tid = threadIdx.x;
    if (blockIdx.x == 0) {
        __shared__ int sums[256];
        int per = (B + 255) / 256;
        int b0 = tid * per;
        int local[32];
        int tot = 0;
        for (int i = 0; i < per && i < 32; ++i) {
            int b = b0 + i;
            int v = (b < B) ? seq_len[b] : 0;
            local[i] = tot;
            tot += v;
        }
        sums[tid] = tot;
        __syncthreads();
        for (int off = 1; off < 256; off <<= 1) {
            int v = (tid >= off) ? sums[tid - off] : 0;
            __syncthreads();
            sums[tid] += v;
            __syncthreads();
        }
        int start = sums[tid] - tot;
        for (int i = 0; i < per && i < 32; ++i) {
            int b = b0 + i;
            if (b < B) offsets[b] = start + local[i];
        }
        if (tid == 255) offsets[B] = sums[255];
    } else {
        int n = blockIdx.x - 1;
        int k = tid;
        WphT[n * HD + k] = f2bf(Wp[k * HD + n]);
        WpbT[n * HD + k] = f2bf(Wp[(HD + k) * HD + n]);
        W2T[n * HD + k]  = f2bf(W2[k * HD + n]);
        W1b[n * HD + k]  = f2bf(W1[n * HD + k]);   // non-transposed bf16 copy
    }
}

// ---------------- K2: blocks [0,B): mean + seg + hb + fused u-GEMV ; blocks [B,B+nbp): P2 tile ----------------
__global__ __launch_bounds__(256) void mean_u_p2_kernel(
    const float* __restrict__ hidden, const int* __restrict__ offsets, int B,
    unsigned short* __restrict__ hb, int* __restrict__ seg,
    const unsigned short* __restrict__ W1b,
    const float* __restrict__ b1, const float* __restrict__ b2,
    float* __restrict__ u,
    const float* __restrict__ pos_table, int Mp,
    const unsigned short* __restrict__ WpbT, const float* __restrict__ bp,
    float* __restrict__ P2) {
    __shared__ float4 part[4][64];
    __shared__ float m_s[HD];
    __shared__ __align__(16) unsigned short As[16][ASTRIDE];
    int tid = threadIdx.x;

    if ((int)blockIdx.x < B) {
        int b = blockIdx.x;
        int s = offsets[b], e = offsets[b + 1];
        for (int t = s + tid; t < e; t += 256) seg[t] = b;
        int g = tid >> 6, c = tid & 63;
        float4 acc = {0.f, 0.f, 0.f, 0.f};
        for (int t = s + g; t < e; t += 4) {
            const float4 v = *reinterpret_cast<const float4*>(hidden + (size_t)t * HD + c * 4);
            acc.x += v.x; acc.y += v.y; acc.z += v.z; acc.w += v.w;
            if (hb) {
                us4 pk;
                pk[0] = f2bf(v.x); pk[1] = f2bf(v.y); pk[2] = f2bf(v.z); pk[3] = f2bf(v.w);
                *reinterpret_cast<us4*>(hb + (size_t)t * HD + c * 4) = pk;
            }
        }
        part[g][c] = acc;
        __syncthreads();
        if (g == 0) {
            float4 a0 = part[0][c], a1 = part[1][c], a2 = part[2][c], a3 = part[3][c];
            float inv = 1.0f / (float)(e - s);
            m_s[c * 4 + 0] = (a0.x + a1.x + a2.x + a3.x) * inv;
            m_s[c * 4 + 1] = (a0.y + a1.y + a2.y + a3.y) * inv;
            m_s[c * 4 + 2] = (a0.z + a1.z + a2.z + a3.z) * inv;
            m_s[c * 4 + 3] = (a0.w + a1.w + a2.w + a3.w) * inv;
        }
        __syncthreads();
        // u[b][n] = sum_k m_s[k] * W1[k][n] + b1[n] + b2[n]   (thread n = tid)
        int n = tid;
        float sacc = 0.f;
        #pragma unroll 4
        for (int k = 0; k < HD; k += 8) {
            float p0 = m_s[k + 0] * bf2f(W1b[(size_t)(k + 0) * HD + n]);
            float p1 = m_s[k + 1] * bf2f(W1b[(size_t)(k + 1) * HD + n]);
            float p2_ = m_s[k + 2] * bf2f(W1b[(size_t)(k + 2) * HD + n]);
            float p3 = m_s[k + 3] * bf2f(W1b[(size_t)(k + 3) * HD + n]);
            float p4 = m_s[k + 4] * bf2f(W1b[(size_t)(k + 4) * HD + n]);
            float p5 = m_s[k + 5] * bf2f(W1b[(size_t)(k + 5) * HD + n]);
            float p6 = m_s[k + 6] * bf2f(W1b[(size_t)(k + 6) * HD + n]);
            float p7 = m_s[k + 7] * bf2f(W1b[(size_t)(k + 7) * HD + n]);
            sacc += ((p0 + p1) + (p2_ + p3)) + ((p4 + p5) + (p6 + p7));
        }
        u[(size_t)b * HD + n] = sacc + b1[n] + b2[n];
    } else {
        // ---- P2 tile: rows m0..m0+15 of tanh-input precompute ----
        int m0 = ((int)blockIdx.x - B) * 16;
        {
            int row = tid >> 4;
            int colg = (tid & 15) * 16;
            int m = m0 + row;
            float4 f[4] = {{0,0,0,0},{0,0,0,0},{0,0,0,0},{0,0,0,0}};
            if (m < Mp) {
                const float4* p = reinterpret_cast<const float4*>(pos_table + (size_t)m * HD + colg);
                f[0] = p[0]; f[1] = p[1]; f[2] = p[2]; f[3] = p[3];
            }
            ushort8v v0, v1;
            v0[0]=f2bf(f[0].x); v0[1]=f2bf(f[0].y); v0[2]=f2bf(f[0].z); v0[3]=f2bf(f[0].w);
            v0[4]=f2bf(f[1].x); v0[5]=f2bf(f[1].y); v0[6]=f2bf(f[1].z); v0[7]=f2bf(f[1].w);
            v1[0]=f2bf(f[2].x); v1[1]=f2bf(f[2].y); v1[2]=f2bf(f[2].z); v1[3]=f2bf(f[2].w);
            v1[4]=f2bf(f[3].x); v1[5]=f2bf(f[3].y); v1[6]=f2bf(f[3].z); v1[7]=f2bf(f[3].w);
            *reinterpret_cast<ushort8v*>(&As[row][colg])     = v0;
            *reinterpret_cast<ushort8v*>(&As[row][colg + 8]) = v1;
        }
        __syncthreads();
        int wave = tid >> 6, lane = tid & 63, quad = lane >> 4, cc = lane & 15;
        int nb = wave * 64;
        f32x4 acc4[4];
        for (int i = 0; i < 4; ++i) acc4[i] = (f32x4){0.f, 0.f, 0.f, 0.f};
        bf16x8 wfp[4];
        for (int nf = 0; nf < 4; ++nf)
            wfp[nf] = *reinterpret_cast<const bf16x8*>(WpbT + (size_t)(nb + nf * 16 + cc) * HD + quad * 8);
        for (int kc8 = 0; kc8 < 8; ++kc8) {
            int kc = kc8 * 32;
            bf16x8 wfc[4];
            for (int nf = 0; nf < 4; ++nf) wfc[nf] = wfp[nf];
            if (kc8 < 7)
                for (int nf = 0; nf < 4; ++nf)
                    wfp[nf] = *reinterpret_cast<const bf16x8*>(WpbT + (size_t)(nb + nf * 16 + cc) * HD + kc + 32 + quad * 8);
            bf16x8 af = *reinterpret_cast<const bf16x8*>(&As[cc][kc + quad * 8]);
            for (int nf = 0; nf < 4; ++nf)
                acc4[nf] = __builtin_amdgcn_mfma_f32_16x16x32_bf16(af, wfc[nf], acc4[nf], 0, 0, 0);
        }
        for (int nf = 0; nf < 4; ++nf)
            for (int r = 0; r < 4; ++r) {
                int row = m0 + quad * 4 + r;
                int col = nb + nf * 16 + cc;
                if (row < Mp)
                    P2[(size_t)row * HD + col] = acc4[nf][r] + bp[col];
            }
    }
}

// ---------------- K3: fused main kernel ----------------
__global__ __launch_bounds__(256, 3) void main_kernel(
    const float* __restrict__ hidden, const unsigned short* __restrict__ hb, int T,
    const unsigned short* __restrict__ WphT,
    const unsigned short* __restrict__ W2T,
    const float* __restrict__ P2,
    const float* __restrict__ u,
    const float* __restrict__ qw, const float* __restrict__ qb,
    const int* __restrict__ rp, const int* __restrict__ seg,
    float* __restrict__ alpha) {
    __shared__ __align__(16) unsigned short Ah[BM][ASTRIDE];   // A tile, then Ph in place
    __shared__ int rp_s[BM];
    __shared__ int seg_s[BM];
    __shared__ float alpha_s[BM];

    int tid = threadIdx.x;
    int t0 = blockIdx.x * BM;
    int wave = tid >> 6, lane = tid & 63, quad = lane >> 4, cc = lane & 15;
    int mb = wave * 64;

    // ---- 4-deep preload of GEMM1 weight frags (kc8 = 0..3) ----
    bf16x8 afp[4][4];
    for (int s = 0; s < 4; ++s)
        for (int mf = 0; mf < 4; ++mf)
            afp[s][mf] = *reinterpret_cast<const bf16x8*>(WphT + (size_t)(mb + mf * 16 + cc) * HD + s * 32 + quad * 8);

    // ---- stage hidden tile -> LDS ----
    {
        int row = tid >> 2;
        int t = t0 + row;
        if (hb) {
            for (int i = 0; i < 8; ++i) {
                int cg = (tid & 3) * 8 + 32 * i;
                ushort8v v = {0,0,0,0,0,0,0,0};
                if (t < T) v = *reinterpret_cast<const ushort8v*>(hb + (size_t)t * HD + cg);
                *reinterpret_cast<ushort8v*>(&Ah[row][cg]) = v;
            }
        } else {
            for (int i = 0; i < 8; ++i) {
                int cg = (tid & 3) * 8 + 32 * i;
                float4 f0 = {0,0,0,0}, f1 = {0,0,0,0};
                if (t < T) {
                    const float4* p = reinterpret_cast<const float4*>(hidden + (size_t)t * HD + cg);
                    f0 = p[0]; f1 = p[1];
                }
                ushort8v pk;
                pk[0] = f2bf(f0.x); pk[1] = f2bf(f0.y); pk[2] = f2bf(f0.z); pk[3] = f2bf(f0.w);
                pk[4] = f2bf(f1.x); pk[5] = f2bf(f1.y); pk[6] = f2bf(f1.z); pk[7] = f2bf(f1.w);
                *reinterpret_cast<ushort8v*>(&Ah[row][cg]) = pk;
            }
        }
    }
    if (tid < BM) {
        int t = t0 + tid;
        rp_s[tid]  = (t < T) ? rp[t] : 0;
        seg_s[tid] = (t < T) ? seg[t] : 0;
        alpha_s[tid] = qb[0];
    }
    __syncthreads();

    f32x4 acc[4][4];
    for (int i = 0; i < 4; ++i) for (int j = 0; j < 4; ++j) acc[i][j] = (f32x4){0.f, 0.f, 0.f, 0.f};

    // ---- GEMM1 (transposed): rows = h, cols = token; 4-deep pipelined weights ----
    for (int kc8 = 0; kc8 < 8; ++kc8) {
        int kc = kc8 * 32;
        int slot = kc8 & 3;
        bf16x8 afc[4];
        for (int mf = 0; mf < 4; ++mf) afc[mf] = afp[slot][mf];
        if (kc8 < 4)
            for (int mf = 0; mf < 4; ++mf)
                afp[slot][mf] = *reinterpret_cast<const bf16x8*>(WphT + (size_t)(mb + mf * 16 + cc) * HD + kc + 128 + quad * 8);
        bf16x8 bfr[4];
        for (int nf = 0; nf < 4; ++nf)
            bfr[nf] = *reinterpret_cast<const bf16x8*>(&Ah[nf * 16 + cc][kc + quad * 8]);
        for (int mf = 0; mf < 4; ++mf)
            for (int nf = 0; nf < 4; ++nf)
                acc[mf][nf] = __builtin_amdgcn_mfma_f32_16x16x32_bf16(afc[mf], bfr[nf], acc[mf][nf], 0, 0, 0);
    }

    // ---- 4-deep preload of GEMM2 weight frags (flies under epilogue-1 VALU) ----
    bf16x8 wfp[4][4];
    for (int s = 0; s < 4; ++s)
        for (int nf = 0; nf < 4; ++nf)
            wfp[s][nf] = *reinterpret_cast<const bf16x8*>(W2T + (size_t)(mb + nf * 16 + cc) * HD + s * 32 + quad * 8);

    __syncthreads();   // all LDS reads of the A tile done

    // ---- epilogue 1: Ph[token][h] = tanh(acc + P2[rp][h]) ----
    for (int mf = 0; mf < 4; ++mf)
        for (int nf = 0; nf < 4; ++nf) {
            int token = nf * 16 + cc;
            int h0 = mb + mf * 16 + quad * 4;
            const float4 p2v = *reinterpret_cast<const float4*>(P2 + (size_t)rp_s[token] * HD + h0);
            us4 pk;
            {
                float v0 = acc[mf][nf][0] + p2v.x;
                float v1 = acc[mf][nf][1] + p2v.y;
                float v2 = acc[mf][nf][2] + p2v.z;
                float v3 = acc[mf][nf][3] + p2v.w;
                float e0 = __expf(2.f * v0), e1 = __expf(2.f * v1);
                float e2 = __expf(2.f * v2), e3 = __expf(2.f * v3);
                pk[0] = f2bf(1.f - 2.f / (e0 + 1.f));
                pk[1] = f2bf(1.f - 2.f / (e1 + 1.f));
                pk[2] = f2bf(1.f - 2.f / (e2 + 1.f));
                pk[3] = f2bf(1.f - 2.f / (e3 + 1.f));
            }
            *reinterpret_cast<us4*>(&Ah[token][h0]) = pk;
            acc[mf][nf] = (f32x4){0.f, 0.f, 0.f, 0.f};
        }
    __syncthreads();

    // ---- GEMM2: rows = token, cols = n; 4-deep pipelined weights ----
    for (int kc8 = 0; kc8 < 8; ++kc8) {
        int kc = kc8 * 32;
        int slot = kc8 & 3;
        bf16x8 wfc[4];
        for (int nf = 0; nf < 4; ++nf) wfc[nf] = wfp[slot][nf];
        if (kc8 < 4)
            for (int nf = 0; nf < 4; ++nf)
                wfp[slot][nf] = *reinterpret_cast<const bf16x8*>(W2T + (size_t)(mb + nf * 16 + cc) * HD + kc + 128 + quad * 8);
        for (int mf = 0; mf < 4; ++mf) {
            bf16x8 af = *reinterpret_cast<const bf16x8*>(&Ah[mf * 16 + cc][kc + quad * 8]);
            for (int nf = 0; nf < 4; ++nf)
                acc[mf][nf] = __builtin_amdgcn_mfma_f32_16x16x32_bf16(af, wfc[nf], acc[mf][nf], 0, 0, 0);
        }
    }

    // ---- epilogue 2: alpha partial = sum_n sigmoid(acc + u[seg][n]) * qw[n] ----
    float qwv[4];
    for (int nf = 0; nf < 4; ++nf) qwv[nf] = qw[mb + nf * 16 + cc];
    for (int mf = 0; mf < 4; ++mf)
        for (int r = 0; r < 4; ++r) {
            int token = mf * 16 + quad * 4 + r;
            const float* urow = u + (size_t)seg_s[token] * HD;
            float s = 0.f;
            for (int nf = 0; nf < 4; ++nf) {
                float g = acc[mf][nf][r] + urow[mb + nf * 16 + cc];
                g = 1.0f / (1.0f + __expf(-g));
                s += g * qwv[nf];
            }
            s += __shfl_xor(s, 1);
            s += __shfl_xor(s, 2);
            s += __shfl_xor(s, 4);
            s += __shfl_xor(s, 8);
            if (cc == 0) atomicAdd(&alpha_s[token], s);
        }
    __syncthreads();
    if (tid < BM) {
        int t = t0 + tid;
        if (t < T) alpha[t] = alpha_s[tid];
    }
}

// ---------------- K4: weighted segment sum -> d_out ----------------
__global__ void hs_kernel(const float* __restrict__ hidden, const unsigned short* __restrict__ hb,
                          const float* __restrict__ alpha,
                          const int* __restrict__ offsets, float* __restrict__ out) {
    int b = blockIdx.x;
    int s = offsets[b], e = offsets[b + 1];
    int tid = threadIdx.x;
    __shared__ float al[256];
    for (int i = tid; i < e - s; i += 256) al[i] = alpha[s + i];
    __syncthreads();
    int g = tid >> 6, c = tid & 63;
    float4 acc = {0.f, 0.f, 0.f, 0.f};
    if (hb) {
        for (int t = s + g; t < e; t += 4) {
            float a = al[t - s];
            us4 v = *reinterpret_cast<const us4*>(hb + (size_t)t * HD + c * 4);
            acc.x += a * bf2f(v[0]);
            acc.y += a * bf2f(v[1]);
            acc.z += a * bf2f(v[2]);
            acc.w += a * bf2f(v[3]);
        }
    } else {
        for (int t = s + g; t < e; t += 4) {
            float a = al[t - s];
            const float4 v = *reinterpret_cast<const float4*>(hidden + (size_t)t * HD + c * 4);
            acc.x += a * v.x; acc.y += a * v.y; acc.z += a * v.z; acc.w += a * v.w;
        }
    }
    __shared__ float4 part[4][64];
    part[g][c] = acc;
    __syncthreads();
    if (g == 0) {
        float4 a0 = part[0][c], a1 = part[1][c], a2 = part[2][c], a3 = part[3][c];
        float4 m;
        m.x = a0.x + a1.x + a2.x + a3.x;
        m.y = a0.y + a1.y + a2.y + a3.y;
        m.z = a0.z + a1.z + a2.z + a3.z;
        m.w = a0.w + a1.w + a2.w + a3.w;
        *reinterpret_cast<float4*>(out + (size_t)b * HD + c * 4) = m;
    }
}

extern "C" void kernel_launch(void* const* d_in, const int* in_sizes, int n_in,
                              void* d_out, int out_size, void* d_ws, size_t ws_size,
                              hipStream_t stream) {
    (void)n_in; (void)out_size;
    const float* hidden    = (const float*)d_in[0];
    const float* pos_table = (const float*)d_in[1];
    const float* W_pos     = (const float*)d_in[2];
    const float* b_pos     = (const float*)d_in[3];
    const float* W1        = (const float*)d_in[4];
    const float* b1        = (const float*)d_in[5];
    const float* W2        = (const float*)d_in[6];
    const float* b2        = (const float*)d_in[7];
    const float* qw        = (const float*)d_in[8];
    const float* qb        = (const float*)d_in[9];
    const int* seq_len     = (const int*)d_in[10];
    const int* reverse_pos = (const int*)d_in[11];

    int T  = in_sizes[0] / HD;
    int B  = in_sizes[10];
    int NP = in_sizes[1] / HD;

    char* ws = (char*)d_ws;
    char* ws_end = ws + ws_size;
    auto carve = [&](size_t bytes) -> char* {
        char* p = ws;
        ws += (bytes + 255) & ~(size_t)255;
        return p;
    };
    int* offsets          = (int*)carve((size_t)(B + 1) * sizeof(int));
    int* seg              = (int*)carve((size_t)T * sizeof(int));
    float* u              = (float*)carve((size_t)B * HD * sizeof(float));
    float* P2             = (float*)carve((size_t)NP * HD * sizeof(float));
    unsigned short* WphT  = (unsigned short*)carve((size_t)HD * HD * 2);
    unsigned short* WpbT  = (unsigned short*)carve((size_t)HD * HD * 2);
    unsigned short* W1b   = (unsigned short*)carve((size_t)HD * HD * 2);
    unsigned short* W2T   = (unsigned short*)carve((size_t)HD * HD * 2);
    float* alpha          = (float*)carve((size_t)T * sizeof(float));
    unsigned short* hb    = nullptr;
    if ((size_t)(ws_end - ws) >= (size_t)T * HD * 2 + 256)
        hb = (unsigned short*)carve((size_t)T * HD * 2);

    int nbp = (NP + 15) / 16;

    setup_kernel<<<HD + 1, 256, 0, stream>>>(seq_len, offsets, B, W_pos, W1, W2,
                                             WphT, WpbT, W1b, W2T);
    mean_u_p2_kernel<<<B + nbp, 256, 0, stream>>>(hidden, offsets, B, hb, seg,
                                                  W1b, b1, b2, u,
                                                  pos_table, NP, WpbT, b_pos, P2);
    main_kernel<<<(T + BM - 1) / BM, 256, 0, stream>>>(hidden, hb, T, WphT, W2T, P2, u, qw, qb,
                                                       reverse_pos, seg, alpha);
    hs_kernel<<<B, 256, 0, stream>>>(hidden, hb, alpha, offsets, (float*)d_out);
}